// Round 12
// baseline (277.841 us; speedup 1.0000x reference)
//
#include <hip/hip_runtime.h>
#include <cstdint>

// Problem dims: N=2048, IN_DIM=128, HID=64, ENC=64, B=64, SEQ=12

typedef _Float16 half8 __attribute__((ext_vector_type(8)));
typedef _Float16 half4 __attribute__((ext_vector_type(4)));
typedef float f32x4 __attribute__((ext_vector_type(4)));

static __device__ inline f32x4 mfma16(half8 a, half8 b, f32x4 c) {
  return __builtin_amdgcn_mfma_f32_16x16x32_f16(a, b, c, 0, 0, 0);
}

static __device__ inline float fast_sigmoid(float x) {
  return __builtin_amdgcn_rcpf(1.f + __expf(-x));
}
static __device__ inline float fast_tanh(float x) {
  return 1.f - 2.f * __builtin_amdgcn_rcpf(__expf(2.f * x) + 1.f);
}

// A/B-fragment half-index for element (n, k), plain layout.
static __device__ inline int afr4(int n, int k) {
  return ((n >> 4) * 2 + (k >> 5)) * 512 +
         (((n & 15) | (((k >> 3) & 3) << 4)) * 8) + (k & 7);
}

// hsOwn with 8-half-block XOR swizzle.
static __device__ inline int hso4(int n, int k) {
  return n * 64 + (((k >> 3) ^ ((n >> 1) & 7)) * 8) + (k & 7);
}

// ---------------------------------------------------------------------------
// E1 fused: x1 + x1f frags (blocks 0..511); prep w1f/w2f/wlf frags + zero
// psum/pqsum (blocks 512..575).
__global__ __launch_bounds__(256) void extract1p(
    const float* __restrict__ h, const float* __restrict__ ew1,
    const float* __restrict__ eb1, const float* __restrict__ w1,
    const float* __restrict__ w2, const float* __restrict__ wl_w,
    float* __restrict__ x1, _Float16* __restrict__ x1f,
    _Float16* __restrict__ w1f, _Float16* __restrict__ w2f,
    _Float16* __restrict__ wlf, float* __restrict__ psums)
{
  const int bx = blockIdx.x, t = threadIdx.x;
  if (bx < 512) {
    int idx = bx * 256 + t;   // 131072 total
    int n = idx >> 6, j = idx & 63;
    const float4* hr = (const float4*)(h + (size_t)n * 128);
    const float4* wr = (const float4*)(ew1 + (size_t)j * 128);
    float acc = eb1[j];
#pragma unroll
    for (int k4 = 0; k4 < 32; ++k4) {
      float4 a = hr[k4], w = wr[k4];
      acc += a.x * w.x + a.y * w.y + a.z * w.z + a.w * w.w;
    }
    x1[idx] = acc;
    int ks = n >> 5, nt = j >> 4;
    int l = (j & 15) | (((n >> 3) & 3) << 4);
    x1f[(((ks * 4 + nt) * 64) + l) * 8 + (n & 7)] = (_Float16)acc;
  } else {
    if (bx == 512 && t < 128) psums[t] = 0.f;
    int idx = (bx - 512) * 256 + t;   // 16384 total
    int e = idx & 7, l = (idx >> 3) & 63;
    int kk = ((l >> 4) * 8) + e;
    if (idx < 8192) {
      int ks = (idx >> 9) & 1, nt = idx >> 10;  // nt 0..7
      int k = ks * 32 + kk;
      w1f[idx] = (_Float16)w1[(1 + k) * 128 + nt * 16 + (l & 15)];
    } else if (idx < 12288) {
      int i2 = idx - 8192;
      int ks = (i2 >> 9) & 1, nt = i2 >> 10;    // nt 0..3
      int k = ks * 32 + kk;
      w2f[i2] = (_Float16)w2[(1 + k) * 64 + nt * 16 + (l & 15)];
    } else {
      int i3 = idx - 12288;
      int ks = (i3 >> 9) & 1, nt = i3 >> 10;    // nt 0..3
      int k = ks * 32 + kk;
      wlf[i3] = (_Float16)wl_w[(nt * 16 + (l & 15)) * 128 + k];
    }
  }
}

// ---------------------------------------------------------------------------
// E2 (MFMA): pooled = adj @ x1, deg = rowsum(adj); x2 = pooled/deg + eps1*x1;
// fused BN partial sums -> atomicAdd into psum/pqsum[64].
__global__ __launch_bounds__(256) void extract2s(
    const float* __restrict__ adj, const float* __restrict__ x1,
    const _Float16* __restrict__ x1f, const float* __restrict__ eps1,
    float* __restrict__ x2, float* __restrict__ psum,
    float* __restrict__ pqsum)
{
  const int n0 = blockIdx.x * 8;
  const int t = threadIdx.x;
  const int l = t & 63, wv = t >> 6;
  __shared__ __align__(16) _Float16 Abuf[4096];
  __shared__ float deg_l[8];

  for (int i = t; i < 4096; i += 256) Abuf[i] = (_Float16)0.f;

  const int row = t >> 5;
  const int kcol = (t & 31) * 8;
  const int s_my = (t & 31) >> 2;
  const int c_my = t & 3;

  float degp = 0.f;
  f32x4 acc = {0.f, 0.f, 0.f, 0.f};

  for (int kc = 0; kc < 8; ++kc) {
    __syncthreads();
    {
      const float* src = &adj[(size_t)(n0 + row) * 2048 + kc * 256 + kcol];
      float4 p0 = *(const float4*)src;
      float4 p1 = *(const float4*)(src + 4);
      degp += p0.x + p0.y + p0.z + p0.w + p1.x + p1.y + p1.z + p1.w;
      half8 v;
      v[0] = (_Float16)p0.x; v[1] = (_Float16)p0.y;
      v[2] = (_Float16)p0.z; v[3] = (_Float16)p0.w;
      v[4] = (_Float16)p1.x; v[5] = (_Float16)p1.y;
      v[6] = (_Float16)p1.z; v[7] = (_Float16)p1.w;
      *(half8*)&Abuf[(size_t)(s_my * 64 + (row | (c_my << 4))) * 8] = v;
    }
    __syncthreads();
#pragma unroll
    for (int s = 0; s < 8; ++s) {
      half8 A = *(half8*)&Abuf[(s * 64 + l) * 8];
      half8 B = *(const half8*)&x1f[(size_t)(((kc * 8 + s) * 4 + wv) * 64 + l) * 8];
      acc = mfma16(A, B, acc);
    }
  }

  for (int sh = 16; sh >= 1; sh >>= 1) degp += __shfl_down(degp, sh, 32);
  if ((t & 31) == 0) deg_l[row] = degp;
  __syncthreads();

  const float ep = eps1[0];
  const int colc = wv * 16 + (l & 15);
  const int r0 = (l >> 4) * 4;
  float ps = 0.f, qs = 0.f;
  if (r0 < 8) {
#pragma unroll
    for (int q = 0; q < 4; ++q) {
      int r = r0 + q;
      float d = deg_l[r];
      d = (d < 1e-6f) ? 1.f : d;
      size_t off = (size_t)(n0 + r) * 64 + colc;
      float xv = acc[q] / d + ep * x1[off];
      x2[off] = xv;
      ps += xv; qs += xv * xv;
    }
  }
  ps += __shfl_down(ps, 16, 64);
  qs += __shfl_down(qs, 16, 64);
  if ((l >> 4) == 0) {
    atomicAdd(&psum[colc], ps);
    atomicAdd(&pqsum[colc], qs);
  }
}

// ---------------------------------------------------------------------------
// E4: scale/shift from psum/pqsum inline; xn; feat; fp; fplC (swapped C').
__global__ __launch_bounds__(256) void extract4s(
    const float* __restrict__ x2, const float* __restrict__ psum,
    const float* __restrict__ pqsum, const float* __restrict__ bnw,
    const float* __restrict__ bnb, const float* __restrict__ ew2,
    const float* __restrict__ eb2, const float* __restrict__ wg,
    const float* __restrict__ bg, const float* __restrict__ wl_w,
    const float* __restrict__ wl_b, _Float16* __restrict__ fplC)
{
  __shared__ float xn[4][64], ft[4][64], fp[4][64];
  __shared__ float scl[64], shf[64];
  int t = threadIdx.x, sub = t >> 6, o = t & 63;
  int n = blockIdx.x * 4 + sub;
  if (t < 64) {
    float s = psum[t], q = pqsum[t];
    float mean = s * (1.f / 2048.f);
    float var = q * (1.f / 2048.f) - mean * mean;
    float rstd = rsqrtf(var + 1e-5f);
    float sc = rstd * bnw[t];
    scl[t] = sc;
    shf[t] = bnb[t] - mean * sc;
  }
  __syncthreads();
  xn[sub][o] = x2[(size_t)n * 64 + o] * scl[o] + shf[o];
  __syncthreads();
  {
    float acc = eb2[o];
    for (int k = 0; k < 64; ++k) acc += xn[sub][k] * ew2[o * 64 + k];
    ft[sub][o] = acc;
  }
  __syncthreads();
  {
    float acc = bg[0];
    for (int k = 0; k < 64; ++k) acc += ft[sub][k] * wg[k * 64 + o];
    fp[sub][o] = acc;
  }
  __syncthreads();
  {
    float acc = wl_b[o];
    for (int k = 0; k < 64; ++k) acc += fp[sub][k] * wl_w[o * 128 + 64 + k];
    int tile = n >> 6;
    int ntp = (n >> 4) & 3;
    int lane = (n & 15) | (((o >> 2) & 3) << 4);
    fplC[(((tile * 4 + (o >> 4)) * 256) + ntp * 64 + lane) * 4 + (o & 3)] =
        (_Float16)acc;
  }
}

// ---------------------------------------------------------------------------
// One GRU step, swapped-operand MFMAs; P1 B-fragments (hs_src) loaded
// DIRECTLY from global (fragment lane-map lines up with row-major hs),
// so the stage phase is hsOwn only. Block: tile=blockIdx.x, batches
// bA=blockIdx.y and bA+32 sequentially. 256 threads = 4 waves.
__global__ __launch_bounds__(256, 4) void gru_step(
    const _Float16* __restrict__ hs_in, void* __restrict__ hs_out_v,
    int outF32, const float* __restrict__ inputs, int tstep, int first,
    const float* __restrict__ w1, const float* __restrict__ b1,
    const float* __restrict__ w2, const float* __restrict__ b2,
    const _Float16* __restrict__ fplC, const _Float16* __restrict__ w1f,
    const _Float16* __restrict__ w2f, const _Float16* __restrict__ wlf)
{
  const int tile = blockIdx.x;
  const int bA   = blockIdx.y;      // 0..31
  const int a = tile * 64;
  const int t = threadIdx.x;
  const int l = t & 63, wv = t >> 6;
  const int lq = l >> 4, li = l & 15;
  const int halfBase = a >> 1;

  __shared__ __align__(16) _Float16 Anew[4096];   // 'new' frags (P2 -> P3)
  __shared__ __align__(16) _Float16 A2f[4096];    // rh frags
  __shared__ __align__(16) _Float16 uF[4096];     // u gates (frag layout)
  __shared__ __align__(16) _Float16 hsOwn[4096];  // own hs, k8-swizzled

  // ---- persistent per-kernel register loads (shared by both batch units)
  half8 Aw1[2][2];
#pragma unroll
  for (int q = 0; q < 2; ++q)
#pragma unroll
    for (int ks = 0; ks < 2; ++ks)
      Aw1[q][ks] = *(const half8*)&w1f[((((2 * wv + q) * 2 + ks) * 64) + l) * 8];
  half8 Aw2[2], Awl[2];
#pragma unroll
  for (int ks = 0; ks < 2; ++ks) {
    Aw2[ks] = *(const half8*)&w2f[(((wv * 2 + ks) * 64) + l) * 8];
    Awl[ks] = *(const half8*)&wlf[(((wv * 2 + ks) * 64) + l) * 8];
  }
  half4 fpl4[4];
#pragma unroll
  for (int nt = 0; nt < 4; ++nt)
    fpl4[nt] = *(const half4*)&fplC[(((tile * 4 + wv) * 256) + nt * 64 + l) * 4];
  float bjR[2][4], w1xR[2][4];
#pragma unroll
  for (int q = 0; q < 2; ++q)
#pragma unroll
    for (int qq = 0; qq < 4; ++qq) {
      int j = (2 * wv + q) * 16 + lq * 4 + qq;
      bjR[q][qq] = b1[j];
      w1xR[q][qq] = w1[j];          // w1 row 0
    }
  float b2R[4], w2xR[4];
#pragma unroll
  for (int qq = 0; qq < 4; ++qq) {
    int o = wv * 16 + lq * 4 + qq;
    b2R[qq] = b2[o];
    w2xR[qq] = w2[o];               // w2 row 0
  }
  const int bit = wv >> 1;          // gate col j>=64 iff wv>=2

  // src-node indices for this thread's 4 B-fragment tiles
  int nsrcR[4];
#pragma unroll
  for (int nt = 0; nt < 4; ++nt) {
    int msrc = nt * 16 + li;
    nsrcR[nt] = (msrc < 32) ? (halfBase + msrc) : (1024 + halfBase + msrc - 32);
  }

  for (int uu = 0; uu < 2; ++uu) {
    const int b = bA + uu * 32;
    const float* xt = inputs + (size_t)(b * 12 + tstep) * 2048;
    const _Float16* hsb = hs_in + (size_t)b * 131072;

    // per-thread xt loads (L1-broadcast; no LDS)
    float xtsR[4], xtoR[4];
#pragma unroll
    for (int nt = 0; nt < 4; ++nt) {
      xtsR[nt] = xt[nsrcR[nt]];
      xtoR[nt] = xt[a + nt * 16 + li];
    }

    __syncthreads();   // LDS safe to overwrite (prev unit's P3 done)

    // ---- stage hsOwn only (k8-swizzled)
    for (int i = t; i < 512; i += 256) {
      int m = i >> 3, k8 = i & 7;
      half8 vo;
      if (first) {
#pragma unroll
        for (int e = 0; e < 8; ++e) vo[e] = (_Float16)0.f;
      } else {
        vo = *(const half8*)&hsb[(size_t)(a + m) * 64 + k8 * 8];
      }
      *(half8*)&hsOwn[m * 64 + ((k8 ^ ((m >> 1) & 7)) * 8)] = vo;
    }
    __syncthreads();

    // ---- P1 (swapped): C'[j][m] = w1^T x hs_src; B-frags direct from global
#pragma unroll
    for (int nt = 0; nt < 4; ++nt) {
      half8 Ba, Bb;
      if (first) {
#pragma unroll
        for (int e = 0; e < 8; ++e) Ba[e] = (_Float16)0.f;
        Bb = Ba;
      } else {
        const _Float16* rsrc = &hsb[(size_t)nsrcR[nt] * 64 + lq * 8];
        Ba = *(const half8*)rsrc;
        Bb = *(const half8*)(rsrc + 32);
      }
      const int n = 2 * ((nt & 1) * 16 + li) + bit;
#pragma unroll
      for (int q = 0; q < 2; ++q) {
        f32x4 acc;
#pragma unroll
        for (int qq = 0; qq < 4; ++qq)
          acc[qq] = bjR[q][qq] + xtsR[nt] * w1xR[q][qq];
        acc = mfma16(Aw1[q][0], Ba, acc);
        acc = mfma16(Aw1[q][1], Bb, acc);
        const int jt = 2 * wv + q;
        const int k0 = (jt & 3) * 16 + lq * 4;
        half4 g4;
#pragma unroll
        for (int qq = 0; qq < 4; ++qq)
          g4[qq] = (_Float16)fast_sigmoid(acc[qq]);
        const int fa = afr4(n, k0);
        if (nt < 2) {       // r-gates: rh = r * hsOwn
          half4 hv = *(half4*)&hsOwn[hso4(n, k0)];
          half4 r4 = g4 * hv;
          *(half4*)&A2f[fa] = r4;
        } else {            // u-gates
          *(half4*)&uF[fa] = g4;
        }
      }
    }
    __syncthreads();

    // ---- P2 (swapped): C'[o][n] = w2^T x rh; fused new = u*hs + (1-u)*c
#pragma unroll
    for (int nt = 0; nt < 4; ++nt) {
      half8 Ba = *(half8*)&A2f[(((nt * 2 + 0) * 64) + l) * 8];
      half8 Bb = *(half8*)&A2f[(((nt * 2 + 1) * 64) + l) * 8];
      f32x4 acc;
#pragma unroll
      for (int qq = 0; qq < 4; ++qq)
        acc[qq] = b2R[qq] + xtoR[nt] * w2xR[qq];
      acc = mfma16(Aw2[0], Ba, acc);
      acc = mfma16(Aw2[1], Bb, acc);
      const int n = nt * 16 + li;
      const int o0 = wv * 16 + lq * 4;
      half4 c4;
#pragma unroll
      for (int qq = 0; qq < 4; ++qq)
        c4[qq] = (_Float16)fast_tanh(acc[qq]);
      const int fa = afr4(n, o0);
      half4 uv = *(half4*)&uF[fa];
      half4 hv = *(half4*)&hsOwn[hso4(n, o0)];
      half4 one = {(_Float16)1.f, (_Float16)1.f, (_Float16)1.f, (_Float16)1.f};
      half4 nw = uv * hv + (one - uv) * c4;
      *(half4*)&Anew[fa] = nw;
    }
    __syncthreads();

    // ---- P3 (swapped): C'[o][n] = wl^T x new + fplC; vector global store
#pragma unroll
    for (int nt = 0; nt < 4; ++nt) {
      half8 Ba = *(half8*)&Anew[(((nt * 2 + 0) * 64) + l) * 8];
      half8 Bb = *(half8*)&Anew[(((nt * 2 + 1) * 64) + l) * 8];
      f32x4 acc;
#pragma unroll
      for (int qq = 0; qq < 4; ++qq)
        acc[qq] = (float)fpl4[nt][qq];
      acc = mfma16(Awl[0], Ba, acc);
      acc = mfma16(Awl[1], Bb, acc);
      const int n = nt * 16 + li;
      const int o0 = wv * 16 + lq * 4;
      const size_t base = (size_t)b * 131072 + (size_t)(a + n) * 64 + o0;
      if (outF32) {
        float4 o4 = make_float4(acc[0], acc[1], acc[2], acc[3]);
        *(float4*)&((float*)hs_out_v)[base] = o4;
      } else {
        half4 o4;
#pragma unroll
        for (int qq = 0; qq < 4; ++qq) o4[qq] = (_Float16)acc[qq];
        *(half4*)&((_Float16*)hs_out_v)[base] = o4;
      }
    }
  }
}

// ---------------------------------------------------------------------------
extern "C" void kernel_launch(void* const* d_in, const int* in_sizes, int n_in,
                              void* d_out, int out_size, void* d_ws, size_t ws_size,
                              hipStream_t stream) {
  const float* h      = (const float*)d_in[0];
  const float* adj    = (const float*)d_in[1];
  const float* inputs = (const float*)d_in[2];
  const float* ew1    = (const float*)d_in[3];
  const float* eb1    = (const float*)d_in[4];
  const float* ew2    = (const float*)d_in[5];
  const float* eb2    = (const float*)d_in[6];
  const float* eps1   = (const float*)d_in[7];
  const float* bnw    = (const float*)d_in[8];
  const float* bnb    = (const float*)d_in[9];
  const float* w1     = (const float*)d_in[10];
  const float* b1     = (const float*)d_in[11];
  const float* w2     = (const float*)d_in[12];
  const float* b2     = (const float*)d_in[13];
  const float* wg     = (const float*)d_in[14];
  const float* bg     = (const float*)d_in[15];
  const float* wl_w   = (const float*)d_in[16];
  const float* wl_b   = (const float*)d_in[17];

  char* ws = (char*)d_ws;

  // ws layout (bytes):
  //  [0, 16777216)           h0 (fp16 hs ping)
  //  [16777216, 33554432)    h1 (fp16 hs pong)
  //    aliased pre-GRU inside h1: x1 (131072 f32), x2 (131072 f32),
  //      x1f (131072 f16), psum (64 f32) + pqsum (64 f32)
  //  [33554432, +262144)     fplC (131072 halfs)
  //  then w1f (8192 halfs), w2f (4096), wlf (4096)
  _Float16* h0H = (_Float16*)ws;
  _Float16* h1H = (_Float16*)(ws + 16777216);
  float* x1    = (float*)h1H;
  float* x2    = x1 + 131072;
  _Float16* x1f = (_Float16*)(x2 + 131072);
  float* psum  = (float*)(x1f + 131072);   // psum[64] then pqsum[64]
  float* pqsum = psum + 64;
  _Float16* fplC = (_Float16*)(ws + 33554432);
  _Float16* w1f  = fplC + 131072;
  _Float16* w2f  = w1f + 8192;
  _Float16* wlf  = w2f + 4096;

  extract1p<<<576, 256, 0, stream>>>(h, ew1, eb1, w1, w2, wl_w,
                                     x1, x1f, w1f, w2f, wlf, psum);
  extract2s<<<256, 256, 0, stream>>>(adj, x1, x1f, eps1, x2, psum, pqsum);
  extract4s<<<512, 256, 0, stream>>>(x2, psum, pqsum, bnw, bnb, ew2, eb2,
                                     wg, bg, wl_w, wl_b, fplC);

  dim3 grid(32, 32);
  for (int t = 0; t < 12; ++t) {
    const _Float16* ibuf = (t & 1) ? h0H : h1H;   // t=0 ignores (first=1)
    void* obuf; int of32 = 0;
    if (t == 11) { obuf = d_out; of32 = 1; }
    else obuf = (t & 1) ? (void*)h1H : (void*)h0H;
    gru_step<<<grid, 256, 0, stream>>>(ibuf, obuf, of32, inputs, t,
                                       (t == 0) ? 1 : 0,
                                       w1, b1, w2, b2, fplC, w1f, w2f, wlf);
  }
}

// Round 13
// 265.784 us; speedup vs baseline: 1.0454x; 1.0454x over previous
//
#include <hip/hip_runtime.h>
#include <cstdint>

// Problem dims: N=2048, IN_DIM=128, HID=64, ENC=64, B=64, SEQ=12

typedef _Float16 half8 __attribute__((ext_vector_type(8)));
typedef _Float16 half4 __attribute__((ext_vector_type(4)));
typedef float f32x4 __attribute__((ext_vector_type(4)));

static __device__ inline f32x4 mfma16(half8 a, half8 b, f32x4 c) {
  return __builtin_amdgcn_mfma_f32_16x16x32_f16(a, b, c, 0, 0, 0);
}

static __device__ inline float fast_sigmoid(float x) {
  return __builtin_amdgcn_rcpf(1.f + __expf(-x));
}
static __device__ inline float fast_tanh(float x) {
  return 1.f - 2.f * __builtin_amdgcn_rcpf(__expf(2.f * x) + 1.f);
}

// A/B-fragment half-index for element (n, k), plain layout.
static __device__ inline int afr4(int n, int k) {
  return ((n >> 4) * 2 + (k >> 5)) * 512 +
         (((n & 15) | (((k >> 3) & 3) << 4)) * 8) + (k & 7);
}

// hsOwn with 8-half-block XOR swizzle.
static __device__ inline int hso4(int n, int k) {
  return n * 64 + (((k >> 3) ^ ((n >> 1) & 7)) * 8) + (k & 7);
}

// ---------------------------------------------------------------------------
// E1 fused: x1 + x1f frags (blocks 0..511); prep w1f/w2f/wlf frags + zero
// psum/pqsum (blocks 512..575).
__global__ __launch_bounds__(256) void extract1p(
    const float* __restrict__ h, const float* __restrict__ ew1,
    const float* __restrict__ eb1, const float* __restrict__ w1,
    const float* __restrict__ w2, const float* __restrict__ wl_w,
    float* __restrict__ x1, _Float16* __restrict__ x1f,
    _Float16* __restrict__ w1f, _Float16* __restrict__ w2f,
    _Float16* __restrict__ wlf, float* __restrict__ psums)
{
  const int bx = blockIdx.x, t = threadIdx.x;
  if (bx < 512) {
    int idx = bx * 256 + t;   // 131072 total
    int n = idx >> 6, j = idx & 63;
    const float4* hr = (const float4*)(h + (size_t)n * 128);
    const float4* wr = (const float4*)(ew1 + (size_t)j * 128);
    float acc = eb1[j];
#pragma unroll
    for (int k4 = 0; k4 < 32; ++k4) {
      float4 a = hr[k4], w = wr[k4];
      acc += a.x * w.x + a.y * w.y + a.z * w.z + a.w * w.w;
    }
    x1[idx] = acc;
    int ks = n >> 5, nt = j >> 4;
    int l = (j & 15) | (((n >> 3) & 3) << 4);
    x1f[(((ks * 4 + nt) * 64) + l) * 8 + (n & 7)] = (_Float16)acc;
  } else {
    if (bx == 512 && t < 128) psums[t] = 0.f;
    int idx = (bx - 512) * 256 + t;   // 16384 total
    int e = idx & 7, l = (idx >> 3) & 63;
    int kk = ((l >> 4) * 8) + e;
    if (idx < 8192) {
      int ks = (idx >> 9) & 1, nt = idx >> 10;  // nt 0..7
      int k = ks * 32 + kk;
      w1f[idx] = (_Float16)w1[(1 + k) * 128 + nt * 16 + (l & 15)];
    } else if (idx < 12288) {
      int i2 = idx - 8192;
      int ks = (i2 >> 9) & 1, nt = i2 >> 10;    // nt 0..3
      int k = ks * 32 + kk;
      w2f[i2] = (_Float16)w2[(1 + k) * 64 + nt * 16 + (l & 15)];
    } else {
      int i3 = idx - 12288;
      int ks = (i3 >> 9) & 1, nt = i3 >> 10;    // nt 0..3
      int k = ks * 32 + kk;
      wlf[i3] = (_Float16)wl_w[(nt * 16 + (l & 15)) * 128 + k];
    }
  }
}

// ---------------------------------------------------------------------------
// E2 (MFMA): pooled = adj @ x1, deg = rowsum(adj); x2 = pooled/deg + eps1*x1;
// fused BN partial sums -> atomicAdd into psum/pqsum[64].
__global__ __launch_bounds__(256) void extract2s(
    const float* __restrict__ adj, const float* __restrict__ x1,
    const _Float16* __restrict__ x1f, const float* __restrict__ eps1,
    float* __restrict__ x2, float* __restrict__ psum,
    float* __restrict__ pqsum)
{
  const int n0 = blockIdx.x * 8;
  const int t = threadIdx.x;
  const int l = t & 63, wv = t >> 6;
  __shared__ __align__(16) _Float16 Abuf[4096];
  __shared__ float deg_l[8];

  for (int i = t; i < 4096; i += 256) Abuf[i] = (_Float16)0.f;

  const int row = t >> 5;
  const int kcol = (t & 31) * 8;
  const int s_my = (t & 31) >> 2;
  const int c_my = t & 3;

  float degp = 0.f;
  f32x4 acc = {0.f, 0.f, 0.f, 0.f};

  for (int kc = 0; kc < 8; ++kc) {
    __syncthreads();
    {
      const float* src = &adj[(size_t)(n0 + row) * 2048 + kc * 256 + kcol];
      float4 p0 = *(const float4*)src;
      float4 p1 = *(const float4*)(src + 4);
      degp += p0.x + p0.y + p0.z + p0.w + p1.x + p1.y + p1.z + p1.w;
      half8 v;
      v[0] = (_Float16)p0.x; v[1] = (_Float16)p0.y;
      v[2] = (_Float16)p0.z; v[3] = (_Float16)p0.w;
      v[4] = (_Float16)p1.x; v[5] = (_Float16)p1.y;
      v[6] = (_Float16)p1.z; v[7] = (_Float16)p1.w;
      *(half8*)&Abuf[(size_t)(s_my * 64 + (row | (c_my << 4))) * 8] = v;
    }
    __syncthreads();
#pragma unroll
    for (int s = 0; s < 8; ++s) {
      half8 A = *(half8*)&Abuf[(s * 64 + l) * 8];
      half8 B = *(const half8*)&x1f[(size_t)(((kc * 8 + s) * 4 + wv) * 64 + l) * 8];
      acc = mfma16(A, B, acc);
    }
  }

  for (int sh = 16; sh >= 1; sh >>= 1) degp += __shfl_down(degp, sh, 32);
  if ((t & 31) == 0) deg_l[row] = degp;
  __syncthreads();

  const float ep = eps1[0];
  const int colc = wv * 16 + (l & 15);
  const int r0 = (l >> 4) * 4;
  float ps = 0.f, qs = 0.f;
  if (r0 < 8) {
#pragma unroll
    for (int q = 0; q < 4; ++q) {
      int r = r0 + q;
      float d = deg_l[r];
      d = (d < 1e-6f) ? 1.f : d;
      size_t off = (size_t)(n0 + r) * 64 + colc;
      float xv = acc[q] / d + ep * x1[off];
      x2[off] = xv;
      ps += xv; qs += xv * xv;
    }
  }
  ps += __shfl_down(ps, 16, 64);
  qs += __shfl_down(qs, 16, 64);
  if ((l >> 4) == 0) {
    atomicAdd(&psum[colc], ps);
    atomicAdd(&pqsum[colc], qs);
  }
}

// ---------------------------------------------------------------------------
// E4: scale/shift from psum/pqsum inline; xn; feat; fp; fplC (swapped C').
__global__ __launch_bounds__(256) void extract4s(
    const float* __restrict__ x2, const float* __restrict__ psum,
    const float* __restrict__ pqsum, const float* __restrict__ bnw,
    const float* __restrict__ bnb, const float* __restrict__ ew2,
    const float* __restrict__ eb2, const float* __restrict__ wg,
    const float* __restrict__ bg, const float* __restrict__ wl_w,
    const float* __restrict__ wl_b, _Float16* __restrict__ fplC)
{
  __shared__ float xn[4][64], ft[4][64], fp[4][64];
  __shared__ float scl[64], shf[64];
  int t = threadIdx.x, sub = t >> 6, o = t & 63;
  int n = blockIdx.x * 4 + sub;
  if (t < 64) {
    float s = psum[t], q = pqsum[t];
    float mean = s * (1.f / 2048.f);
    float var = q * (1.f / 2048.f) - mean * mean;
    float rstd = rsqrtf(var + 1e-5f);
    float sc = rstd * bnw[t];
    scl[t] = sc;
    shf[t] = bnb[t] - mean * sc;
  }
  __syncthreads();
  xn[sub][o] = x2[(size_t)n * 64 + o] * scl[o] + shf[o];
  __syncthreads();
  {
    float acc = eb2[o];
    for (int k = 0; k < 64; ++k) acc += xn[sub][k] * ew2[o * 64 + k];
    ft[sub][o] = acc;
  }
  __syncthreads();
  {
    float acc = bg[0];
    for (int k = 0; k < 64; ++k) acc += ft[sub][k] * wg[k * 64 + o];
    fp[sub][o] = acc;
  }
  __syncthreads();
  {
    float acc = wl_b[o];
    for (int k = 0; k < 64; ++k) acc += fp[sub][k] * wl_w[o * 128 + 64 + k];
    int tile = n >> 6;
    int ntp = (n >> 4) & 3;
    int lane = (n & 15) | (((o >> 2) & 3) << 4);
    fplC[(((tile * 4 + (o >> 4)) * 256) + ntp * 64 + lane) * 4 + (o & 3)] =
        (_Float16)acc;
  }
}

// ---------------------------------------------------------------------------
// One GRU step, SWAPPED-operand MFMAs (C' = [out-col][node]); R11 structure.
// first=1 takes a bit-exact reduced path (hs=0): no staging, no P1/P2 MFMAs,
// no r-gates; only u = sigmoid(b1+xt*w1row0), c = tanh(b2+xt*w2row0),
// new = (1-u)*c, and P3's MFMA.
__global__ __launch_bounds__(256, 4) void gru_step(
    const _Float16* __restrict__ hs_in, void* __restrict__ hs_out_v,
    int outF32, const float* __restrict__ inputs, int tstep, int first,
    const float* __restrict__ w1, const float* __restrict__ b1,
    const float* __restrict__ w2, const float* __restrict__ b2,
    const _Float16* __restrict__ fplC, const _Float16* __restrict__ w1f,
    const _Float16* __restrict__ w2f, const _Float16* __restrict__ wlf)
{
  const int tile = blockIdx.x;
  const int bA   = blockIdx.y;      // 0..31
  const int a = tile * 64;
  const int t = threadIdx.x;
  const int l = t & 63, wv = t >> 6;
  const int lq = l >> 4, li = l & 15;
  const int halfBase = a >> 1;

  __shared__ __align__(16) _Float16 Asrc[4096];   // hs_src frags -> new frags
  __shared__ __align__(16) _Float16 A2f[4096];    // rh frags
  __shared__ __align__(16) _Float16 uF[4096];     // u gates (frag layout)
  __shared__ __align__(16) _Float16 hsOwn[4096];  // own hs, k8-swizzled
  __shared__ float xts[64], xto[64];

  // ---- persistent per-kernel register loads (shared by both batch units)
  half8 Aw1[2][2];
#pragma unroll
  for (int q = 0; q < 2; ++q)
#pragma unroll
    for (int ks = 0; ks < 2; ++ks)
      Aw1[q][ks] = *(const half8*)&w1f[((((2 * wv + q) * 2 + ks) * 64) + l) * 8];
  half8 Aw2[2], Awl[2];
#pragma unroll
  for (int ks = 0; ks < 2; ++ks) {
    Aw2[ks] = *(const half8*)&w2f[(((wv * 2 + ks) * 64) + l) * 8];
    Awl[ks] = *(const half8*)&wlf[(((wv * 2 + ks) * 64) + l) * 8];
  }
  half4 fpl4[4];
#pragma unroll
  for (int nt = 0; nt < 4; ++nt)
    fpl4[nt] = *(const half4*)&fplC[(((tile * 4 + wv) * 256) + nt * 64 + l) * 4];
  float bjR[2][4], w1xR[2][4];
#pragma unroll
  for (int q = 0; q < 2; ++q)
#pragma unroll
    for (int qq = 0; qq < 4; ++qq) {
      int j = (2 * wv + q) * 16 + lq * 4 + qq;
      bjR[q][qq] = b1[j];
      w1xR[q][qq] = w1[j];          // w1 row 0
    }
  float b2R[4], w2xR[4];
#pragma unroll
  for (int qq = 0; qq < 4; ++qq) {
    int o = wv * 16 + lq * 4 + qq;
    b2R[qq] = b2[o];
    w2xR[qq] = w2[o];               // w2 row 0
  }
  const int bit = wv >> 1;          // gate col j>=64 iff wv>=2

  for (int uu = 0; uu < 2; ++uu) {
    const int b = bA + uu * 32;
    const float* xt = inputs + (size_t)(b * 12 + tstep) * 2048;
    const _Float16* hsb = hs_in + (size_t)b * 131072;

    __syncthreads();   // LDS safe to overwrite

    if (t < 64) {
      xto[t] = xt[a + t];
    } else if (t < 128) {
      int m = t - 64;
      int ns = (m < 32) ? (halfBase + m) : (1024 + halfBase + m - 32);
      xts[m] = xt[ns];
    }
    if (!first) {
      for (int i = t; i < 512; i += 256) {
        int m = i >> 3, k8 = i & 7;
        int ns = (m < 32) ? (halfBase + m) : (1024 + halfBase + m - 32);
        half8 v  = *(const half8*)&hsb[(size_t)ns * 64 + k8 * 8];
        half8 vo = *(const half8*)&hsb[(size_t)(a + m) * 64 + k8 * 8];
        int mt = m >> 4, ks = k8 >> 2, kc = k8 & 3;
        *(half8*)&Asrc[(((mt * 2 + ks) * 64) + ((m & 15) | (kc << 4))) * 8] = v;
        *(half8*)&hsOwn[m * 64 + ((k8 ^ ((m >> 1) & 7)) * 8)] = vo;
      }
    }
    __syncthreads();

    float xtsR[4], xtoR[4];
#pragma unroll
    for (int nt = 0; nt < 4; ++nt) {
      xtsR[nt] = xts[nt * 16 + li];
      xtoR[nt] = xto[nt * 16 + li];
    }

    if (first) {
      // ---- reduced P1: only u-gates, no MFMA (hs=0 -> contribution 0)
#pragma unroll
      for (int nt = 2; nt < 4; ++nt) {
        const int n = 2 * ((nt & 1) * 16 + li) + bit;
#pragma unroll
        for (int q = 0; q < 2; ++q) {
          const int jt = 2 * wv + q;
          const int k0 = (jt & 3) * 16 + lq * 4;
          half4 g4;
#pragma unroll
          for (int qq = 0; qq < 4; ++qq)
            g4[qq] = (_Float16)fast_sigmoid(bjR[q][qq] + xtsR[nt] * w1xR[q][qq]);
          *(half4*)&uF[afr4(n, k0)] = g4;
        }
      }
      __syncthreads();
      // ---- reduced P2: c = tanh(b2 + xt*w2row0); new = (1-u)*c
#pragma unroll
      for (int nt = 0; nt < 4; ++nt) {
        const int n = nt * 16 + li;
        const int o0 = wv * 16 + lq * 4;
        half4 c4;
#pragma unroll
        for (int qq = 0; qq < 4; ++qq)
          c4[qq] = (_Float16)fast_tanh(b2R[qq] + xtoR[nt] * w2xR[qq]);
        const int fa = afr4(n, o0);
        half4 uv = *(half4*)&uF[fa];
        half4 one = {(_Float16)1.f, (_Float16)1.f, (_Float16)1.f, (_Float16)1.f};
        half4 nw = (one - uv) * c4;
        *(half4*)&Asrc[fa] = nw;
      }
      __syncthreads();
    } else {
      // ---- P1 (swapped): C'[j][m] = w1^T x hs_src
#pragma unroll
      for (int nt = 0; nt < 4; ++nt) {
        half8 Ba = *(half8*)&Asrc[(((nt * 2 + 0) * 64) + l) * 8];
        half8 Bb = *(half8*)&Asrc[(((nt * 2 + 1) * 64) + l) * 8];
        const int n = 2 * ((nt & 1) * 16 + li) + bit;
#pragma unroll
        for (int q = 0; q < 2; ++q) {
          f32x4 acc;
#pragma unroll
          for (int qq = 0; qq < 4; ++qq)
            acc[qq] = bjR[q][qq] + xtsR[nt] * w1xR[q][qq];
          acc = mfma16(Aw1[q][0], Ba, acc);
          acc = mfma16(Aw1[q][1], Bb, acc);
          const int jt = 2 * wv + q;
          const int k0 = (jt & 3) * 16 + lq * 4;
          half4 g4;
#pragma unroll
          for (int qq = 0; qq < 4; ++qq)
            g4[qq] = (_Float16)fast_sigmoid(acc[qq]);
          const int fa = afr4(n, k0);
          if (nt < 2) {       // r-gates: rh = r * hsOwn
            half4 hv = *(half4*)&hsOwn[hso4(n, k0)];
            half4 r4 = g4 * hv;
            *(half4*)&A2f[fa] = r4;
          } else {            // u-gates
            *(half4*)&uF[fa] = g4;
          }
        }
      }
      __syncthreads();

      // ---- P2 (swapped): C'[o][n] = w2^T x rh; fused new = u*hs + (1-u)*c
#pragma unroll
      for (int nt = 0; nt < 4; ++nt) {
        half8 Ba = *(half8*)&A2f[(((nt * 2 + 0) * 64) + l) * 8];
        half8 Bb = *(half8*)&A2f[(((nt * 2 + 1) * 64) + l) * 8];
        f32x4 acc;
#pragma unroll
        for (int qq = 0; qq < 4; ++qq)
          acc[qq] = b2R[qq] + xtoR[nt] * w2xR[qq];
        acc = mfma16(Aw2[0], Ba, acc);
        acc = mfma16(Aw2[1], Bb, acc);
        const int n = nt * 16 + li;
        const int o0 = wv * 16 + lq * 4;
        half4 c4;
#pragma unroll
        for (int qq = 0; qq < 4; ++qq)
          c4[qq] = (_Float16)fast_tanh(acc[qq]);
        const int fa = afr4(n, o0);
        half4 uv = *(half4*)&uF[fa];
        half4 hv = *(half4*)&hsOwn[hso4(n, o0)];
        half4 one = {(_Float16)1.f, (_Float16)1.f, (_Float16)1.f, (_Float16)1.f};
        half4 nw = uv * hv + (one - uv) * c4;
        *(half4*)&Asrc[fa] = nw;
      }
      __syncthreads();
    }

    // ---- P3 (swapped): C'[o][n] = wl^T x new + fplC; vector global store
#pragma unroll
    for (int nt = 0; nt < 4; ++nt) {
      half8 Ba = *(half8*)&Asrc[(((nt * 2 + 0) * 64) + l) * 8];
      half8 Bb = *(half8*)&Asrc[(((nt * 2 + 1) * 64) + l) * 8];
      f32x4 acc;
#pragma unroll
      for (int qq = 0; qq < 4; ++qq)
        acc[qq] = (float)fpl4[nt][qq];
      acc = mfma16(Awl[0], Ba, acc);
      acc = mfma16(Awl[1], Bb, acc);
      const int n = nt * 16 + li;
      const int o0 = wv * 16 + lq * 4;
      const size_t base = (size_t)b * 131072 + (size_t)(a + n) * 64 + o0;
      if (outF32) {
        float4 o4 = make_float4(acc[0], acc[1], acc[2], acc[3]);
        *(float4*)&((float*)hs_out_v)[base] = o4;
      } else {
        half4 o4;
#pragma unroll
        for (int qq = 0; qq < 4; ++qq) o4[qq] = (_Float16)acc[qq];
        *(half4*)&((_Float16*)hs_out_v)[base] = o4;
      }
    }
  }
}

// ---------------------------------------------------------------------------
extern "C" void kernel_launch(void* const* d_in, const int* in_sizes, int n_in,
                              void* d_out, int out_size, void* d_ws, size_t ws_size,
                              hipStream_t stream) {
  const float* h      = (const float*)d_in[0];
  const float* adj    = (const float*)d_in[1];
  const float* inputs = (const float*)d_in[2];
  const float* ew1    = (const float*)d_in[3];
  const float* eb1    = (const float*)d_in[4];
  const float* ew2    = (const float*)d_in[5];
  const float* eb2    = (const float*)d_in[6];
  const float* eps1   = (const float*)d_in[7];
  const float* bnw    = (const float*)d_in[8];
  const float* bnb    = (const float*)d_in[9];
  const float* w1     = (const float*)d_in[10];
  const float* b1     = (const float*)d_in[11];
  const float* w2     = (const float*)d_in[12];
  const float* b2     = (const float*)d_in[13];
  const float* wg     = (const float*)d_in[14];
  const float* bg     = (const float*)d_in[15];
  const float* wl_w   = (const float*)d_in[16];
  const float* wl_b   = (const float*)d_in[17];

  char* ws = (char*)d_ws;

  // ws layout (bytes):
  //  [0, 16777216)           h0 (fp16 hs ping)
  //  [16777216, 33554432)    h1 (fp16 hs pong)
  //    aliased pre-GRU inside h1: x1 (131072 f32), x2 (131072 f32),
  //      x1f (131072 f16), psum (64 f32) + pqsum (64 f32)
  //  [33554432, +262144)     fplC (131072 halfs)
  //  then w1f (8192 halfs), w2f (4096), wlf (4096)
  _Float16* h0H = (_Float16*)ws;
  _Float16* h1H = (_Float16*)(ws + 16777216);
  float* x1    = (float*)h1H;
  float* x2    = x1 + 131072;
  _Float16* x1f = (_Float16*)(x2 + 131072);
  float* psum  = (float*)(x1f + 131072);   // psum[64] then pqsum[64]
  float* pqsum = psum + 64;
  _Float16* fplC = (_Float16*)(ws + 33554432);
  _Float16* w1f  = fplC + 131072;
  _Float16* w2f  = w1f + 8192;
  _Float16* wlf  = w2f + 4096;

  extract1p<<<576, 256, 0, stream>>>(h, ew1, eb1, w1, w2, wl_w,
                                     x1, x1f, w1f, w2f, wlf, psum);
  extract2s<<<256, 256, 0, stream>>>(adj, x1, x1f, eps1, x2, psum, pqsum);
  extract4s<<<512, 256, 0, stream>>>(x2, psum, pqsum, bnw, bnb, ew2, eb2,
                                     wg, bg, wl_w, wl_b, fplC);

  dim3 grid(32, 32);
  for (int t = 0; t < 12; ++t) {
    const _Float16* ibuf = (t & 1) ? h0H : h1H;   // t=0 ignores (first=1)
    void* obuf; int of32 = 0;
    if (t == 11) { obuf = d_out; of32 = 1; }
    else obuf = (t & 1) ? (void*)h1H : (void*)h0H;
    gru_step<<<grid, 256, 0, stream>>>(ibuf, obuf, of32, inputs, t,
                                       (t == 0) ? 1 : 0,
                                       w1, b1, w2, b2, fplC, w1f, w2f, wlf);
  }
}

// Round 14
// 242.548 us; speedup vs baseline: 1.1455x; 1.0958x over previous
//
#include <hip/hip_runtime.h>
#include <cstdint>

// Problem dims: N=2048, IN_DIM=128, HID=64, ENC=64, B=64, SEQ=12

typedef _Float16 half8 __attribute__((ext_vector_type(8)));
typedef _Float16 half4 __attribute__((ext_vector_type(4)));
typedef float f32x4 __attribute__((ext_vector_type(4)));

static __device__ inline f32x4 mfma16(half8 a, half8 b, f32x4 c) {
  return __builtin_amdgcn_mfma_f32_16x16x32_f16(a, b, c, 0, 0, 0);
}

static __device__ inline float fast_sigmoid(float x) {
  return __builtin_amdgcn_rcpf(1.f + __expf(-x));
}
static __device__ inline float fast_tanh(float x) {
  return 1.f - 2.f * __builtin_amdgcn_rcpf(__expf(2.f * x) + 1.f);
}

// A/B-fragment half-index for element (n, k), plain layout.
static __device__ inline int afr4(int n, int k) {
  return ((n >> 4) * 2 + (k >> 5)) * 512 +
         (((n & 15) | (((k >> 3) & 3) << 4)) * 8) + (k & 7);
}

// hsOwn with 8-half-block XOR swizzle.
static __device__ inline int hso4(int n, int k) {
  return n * 64 + (((k >> 3) ^ ((n >> 1) & 7)) * 8) + (k & 7);
}

// ---------------------------------------------------------------------------
// E1 fused: x1 + x1f frags (blocks 0..511); prep w1f/w2f/wlf frags + zero
// psum/pqsum (blocks 512..575).
__global__ __launch_bounds__(256) void extract1p(
    const float* __restrict__ h, const float* __restrict__ ew1,
    const float* __restrict__ eb1, const float* __restrict__ w1,
    const float* __restrict__ w2, const float* __restrict__ wl_w,
    float* __restrict__ x1, _Float16* __restrict__ x1f,
    _Float16* __restrict__ w1f, _Float16* __restrict__ w2f,
    _Float16* __restrict__ wlf, float* __restrict__ psums)
{
  const int bx = blockIdx.x, t = threadIdx.x;
  if (bx < 512) {
    int idx = bx * 256 + t;   // 131072 total
    int n = idx >> 6, j = idx & 63;
    const float4* hr = (const float4*)(h + (size_t)n * 128);
    const float4* wr = (const float4*)(ew1 + (size_t)j * 128);
    float acc = eb1[j];
#pragma unroll
    for (int k4 = 0; k4 < 32; ++k4) {
      float4 a = hr[k4], w = wr[k4];
      acc += a.x * w.x + a.y * w.y + a.z * w.z + a.w * w.w;
    }
    x1[idx] = acc;
    int ks = n >> 5, nt = j >> 4;
    int l = (j & 15) | (((n >> 3) & 3) << 4);
    x1f[(((ks * 4 + nt) * 64) + l) * 8 + (n & 7)] = (_Float16)acc;
  } else {
    if (bx == 512 && t < 128) psums[t] = 0.f;
    int idx = (bx - 512) * 256 + t;   // 16384 total
    int e = idx & 7, l = (idx >> 3) & 63;
    int kk = ((l >> 4) * 8) + e;
    if (idx < 8192) {
      int ks = (idx >> 9) & 1, nt = idx >> 10;  // nt 0..7
      int k = ks * 32 + kk;
      w1f[idx] = (_Float16)w1[(1 + k) * 128 + nt * 16 + (l & 15)];
    } else if (idx < 12288) {
      int i2 = idx - 8192;
      int ks = (i2 >> 9) & 1, nt = i2 >> 10;    // nt 0..3
      int k = ks * 32 + kk;
      w2f[i2] = (_Float16)w2[(1 + k) * 64 + nt * 16 + (l & 15)];
    } else {
      int i3 = idx - 12288;
      int ks = (i3 >> 9) & 1, nt = i3 >> 10;    // nt 0..3
      int k = ks * 32 + kk;
      wlf[i3] = (_Float16)wl_w[(nt * 16 + (l & 15)) * 128 + k];
    }
  }
}

// ---------------------------------------------------------------------------
// E2 (MFMA): pooled = adj @ x1, deg = rowsum(adj); x2 = pooled/deg + eps1*x1;
// fused BN partial sums -> atomicAdd into psum/pqsum[64].
__global__ __launch_bounds__(256) void extract2s(
    const float* __restrict__ adj, const float* __restrict__ x1,
    const _Float16* __restrict__ x1f, const float* __restrict__ eps1,
    float* __restrict__ x2, float* __restrict__ psum,
    float* __restrict__ pqsum)
{
  const int n0 = blockIdx.x * 8;
  const int t = threadIdx.x;
  const int l = t & 63, wv = t >> 6;
  __shared__ __align__(16) _Float16 Abuf[4096];
  __shared__ float deg_l[8];

  for (int i = t; i < 4096; i += 256) Abuf[i] = (_Float16)0.f;

  const int row = t >> 5;
  const int kcol = (t & 31) * 8;
  const int s_my = (t & 31) >> 2;
  const int c_my = t & 3;

  float degp = 0.f;
  f32x4 acc = {0.f, 0.f, 0.f, 0.f};

  for (int kc = 0; kc < 8; ++kc) {
    __syncthreads();
    {
      const float* src = &adj[(size_t)(n0 + row) * 2048 + kc * 256 + kcol];
      float4 p0 = *(const float4*)src;
      float4 p1 = *(const float4*)(src + 4);
      degp += p0.x + p0.y + p0.z + p0.w + p1.x + p1.y + p1.z + p1.w;
      half8 v;
      v[0] = (_Float16)p0.x; v[1] = (_Float16)p0.y;
      v[2] = (_Float16)p0.z; v[3] = (_Float16)p0.w;
      v[4] = (_Float16)p1.x; v[5] = (_Float16)p1.y;
      v[6] = (_Float16)p1.z; v[7] = (_Float16)p1.w;
      *(half8*)&Abuf[(size_t)(s_my * 64 + (row | (c_my << 4))) * 8] = v;
    }
    __syncthreads();
#pragma unroll
    for (int s = 0; s < 8; ++s) {
      half8 A = *(half8*)&Abuf[(s * 64 + l) * 8];
      half8 B = *(const half8*)&x1f[(size_t)(((kc * 8 + s) * 4 + wv) * 64 + l) * 8];
      acc = mfma16(A, B, acc);
    }
  }

  for (int sh = 16; sh >= 1; sh >>= 1) degp += __shfl_down(degp, sh, 32);
  if ((t & 31) == 0) deg_l[row] = degp;
  __syncthreads();

  const float ep = eps1[0];
  const int colc = wv * 16 + (l & 15);
  const int r0 = (l >> 4) * 4;
  float ps = 0.f, qs = 0.f;
  if (r0 < 8) {
#pragma unroll
    for (int q = 0; q < 4; ++q) {
      int r = r0 + q;
      float d = deg_l[r];
      d = (d < 1e-6f) ? 1.f : d;
      size_t off = (size_t)(n0 + r) * 64 + colc;
      float xv = acc[q] / d + ep * x1[off];
      x2[off] = xv;
      ps += xv; qs += xv * xv;
    }
  }
  ps += __shfl_down(ps, 16, 64);
  qs += __shfl_down(qs, 16, 64);
  if ((l >> 4) == 0) {
    atomicAdd(&psum[colc], ps);
    atomicAdd(&pqsum[colc], qs);
  }
}

// ---------------------------------------------------------------------------
// E4: scale/shift from psum/pqsum inline; xn; feat; fp; fplC (swapped C').
__global__ __launch_bounds__(256) void extract4s(
    const float* __restrict__ x2, const float* __restrict__ psum,
    const float* __restrict__ pqsum, const float* __restrict__ bnw,
    const float* __restrict__ bnb, const float* __restrict__ ew2,
    const float* __restrict__ eb2, const float* __restrict__ wg,
    const float* __restrict__ bg, const float* __restrict__ wl_w,
    const float* __restrict__ wl_b, _Float16* __restrict__ fplC)
{
  __shared__ float xn[4][64], ft[4][64], fp[4][64];
  __shared__ float scl[64], shf[64];
  int t = threadIdx.x, sub = t >> 6, o = t & 63;
  int n = blockIdx.x * 4 + sub;
  if (t < 64) {
    float s = psum[t], q = pqsum[t];
    float mean = s * (1.f / 2048.f);
    float var = q * (1.f / 2048.f) - mean * mean;
    float rstd = rsqrtf(var + 1e-5f);
    float sc = rstd * bnw[t];
    scl[t] = sc;
    shf[t] = bnb[t] - mean * sc;
  }
  __syncthreads();
  xn[sub][o] = x2[(size_t)n * 64 + o] * scl[o] + shf[o];
  __syncthreads();
  {
    float acc = eb2[o];
    for (int k = 0; k < 64; ++k) acc += xn[sub][k] * ew2[o * 64 + k];
    ft[sub][o] = acc;
  }
  __syncthreads();
  {
    float acc = bg[0];
    for (int k = 0; k < 64; ++k) acc += ft[sub][k] * wg[k * 64 + o];
    fp[sub][o] = acc;
  }
  __syncthreads();
  {
    float acc = wl_b[o];
    for (int k = 0; k < 64; ++k) acc += fp[sub][k] * wl_w[o * 128 + 64 + k];
    int tile = n >> 6;
    int ntp = (n >> 4) & 3;
    int lane = (n & 15) | (((o >> 2) & 3) << 4);
    fplC[(((tile * 4 + (o >> 4)) * 256) + ntp * 64 + lane) * 4 + (o & 3)] =
        (_Float16)acc;
  }
}

// ---------------------------------------------------------------------------
// Step 0 only (hs = 0), SEPARATE kernel so the main kernel's codegen is
// untouched. Bit-exact reduced math: u = sigmoid(b1 + xt*w1row0),
// c = tanh(b2 + xt*w2row0), new = (1-u)*c, out = fplC + new @ wlT (fp16).
__global__ __launch_bounds__(256, 4) void gru_step_first(
    _Float16* __restrict__ hs_out, const float* __restrict__ inputs,
    const float* __restrict__ w1, const float* __restrict__ b1,
    const float* __restrict__ w2, const float* __restrict__ b2,
    const _Float16* __restrict__ fplC, const _Float16* __restrict__ wlf)
{
  const int tile = blockIdx.x;
  const int bA   = blockIdx.y;
  const int a = tile * 64;
  const int t = threadIdx.x;
  const int l = t & 63, wv = t >> 6;
  const int lq = l >> 4, li = l & 15;
  const int halfBase = a >> 1;

  __shared__ __align__(16) _Float16 Anew[4096];
  __shared__ __align__(16) _Float16 uF[4096];
  __shared__ float xts[64], xto[64];

  half8 Awl[2];
#pragma unroll
  for (int ks = 0; ks < 2; ++ks)
    Awl[ks] = *(const half8*)&wlf[(((wv * 2 + ks) * 64) + l) * 8];
  half4 fpl4[4];
#pragma unroll
  for (int nt = 0; nt < 4; ++nt)
    fpl4[nt] = *(const half4*)&fplC[(((tile * 4 + wv) * 256) + nt * 64 + l) * 4];
  float bjR[2][4], w1xR[2][4];
#pragma unroll
  for (int q = 0; q < 2; ++q)
#pragma unroll
    for (int qq = 0; qq < 4; ++qq) {
      int j = (2 * wv + q) * 16 + lq * 4 + qq;
      bjR[q][qq] = b1[j];
      w1xR[q][qq] = w1[j];
    }
  float b2R[4], w2xR[4];
#pragma unroll
  for (int qq = 0; qq < 4; ++qq) {
    int o = wv * 16 + lq * 4 + qq;
    b2R[qq] = b2[o];
    w2xR[qq] = w2[o];
  }
  const int bit = wv >> 1;

  for (int uu = 0; uu < 2; ++uu) {
    const int b = bA + uu * 32;
    const float* xt = inputs + (size_t)(b * 12 + 0) * 2048;

    __syncthreads();
    if (t < 64) {
      xto[t] = xt[a + t];
    } else if (t < 128) {
      int m = t - 64;
      int ns = (m < 32) ? (halfBase + m) : (1024 + halfBase + m - 32);
      xts[m] = xt[ns];
    }
    __syncthreads();

    float xtsR[4], xtoR[4];
#pragma unroll
    for (int nt = 0; nt < 4; ++nt) {
      xtsR[nt] = xts[nt * 16 + li];
      xtoR[nt] = xto[nt * 16 + li];
    }

    // reduced P1: u-gates only (source rows m>=32 -> nt 2,3); MFMA term = 0
#pragma unroll
    for (int nt = 2; nt < 4; ++nt) {
      const int n = 2 * ((nt & 1) * 16 + li) + bit;
#pragma unroll
      for (int q = 0; q < 2; ++q) {
        const int jt = 2 * wv + q;
        const int k0 = (jt & 3) * 16 + lq * 4;
        half4 g4;
#pragma unroll
        for (int qq = 0; qq < 4; ++qq)
          g4[qq] = (_Float16)fast_sigmoid(bjR[q][qq] + xtsR[nt] * w1xR[q][qq]);
        *(half4*)&uF[afr4(n, k0)] = g4;
      }
    }
    __syncthreads();

    // reduced P2: c = tanh(b2 + xt*w2row0); new = (1-u)*c
#pragma unroll
    for (int nt = 0; nt < 4; ++nt) {
      const int n = nt * 16 + li;
      const int o0 = wv * 16 + lq * 4;
      half4 c4;
#pragma unroll
      for (int qq = 0; qq < 4; ++qq)
        c4[qq] = (_Float16)fast_tanh(b2R[qq] + xtoR[nt] * w2xR[qq]);
      const int fa = afr4(n, o0);
      half4 uv = *(half4*)&uF[fa];
      half4 one = {(_Float16)1.f, (_Float16)1.f, (_Float16)1.f, (_Float16)1.f};
      *(half4*)&Anew[fa] = (one - uv) * c4;
    }
    __syncthreads();

    // P3: out = fplC + new @ wlT
#pragma unroll
    for (int nt = 0; nt < 4; ++nt) {
      half8 Ba = *(half8*)&Anew[(((nt * 2 + 0) * 64) + l) * 8];
      half8 Bb = *(half8*)&Anew[(((nt * 2 + 1) * 64) + l) * 8];
      f32x4 acc;
#pragma unroll
      for (int qq = 0; qq < 4; ++qq)
        acc[qq] = (float)fpl4[nt][qq];
      acc = mfma16(Awl[0], Ba, acc);
      acc = mfma16(Awl[1], Bb, acc);
      const int n = nt * 16 + li;
      const int o0 = wv * 16 + lq * 4;
      half4 o4;
#pragma unroll
      for (int qq = 0; qq < 4; ++qq) o4[qq] = (_Float16)acc[qq];
      *(half4*)&hs_out[(size_t)b * 131072 + (size_t)(a + n) * 64 + o0] = o4;
    }
  }
}

// ---------------------------------------------------------------------------
// Steps 1..11 (hs always read). EXACT R11 structure — swapped-operand MFMAs,
// half4-vectorized epilogues, 2 batch units per block.
__global__ __launch_bounds__(256, 4) void gru_step(
    const _Float16* __restrict__ hs_in, void* __restrict__ hs_out_v,
    int outF32, const float* __restrict__ inputs, int tstep,
    const float* __restrict__ w1, const float* __restrict__ b1,
    const float* __restrict__ w2, const float* __restrict__ b2,
    const _Float16* __restrict__ fplC, const _Float16* __restrict__ w1f,
    const _Float16* __restrict__ w2f, const _Float16* __restrict__ wlf)
{
  const int tile = blockIdx.x;
  const int bA   = blockIdx.y;      // 0..31
  const int a = tile * 64;
  const int t = threadIdx.x;
  const int l = t & 63, wv = t >> 6;
  const int lq = l >> 4, li = l & 15;
  const int halfBase = a >> 1;

  __shared__ __align__(16) _Float16 Asrc[4096];   // hs_src frags -> new frags
  __shared__ __align__(16) _Float16 A2f[4096];    // rh frags
  __shared__ __align__(16) _Float16 uF[4096];     // u gates (frag layout)
  __shared__ __align__(16) _Float16 hsOwn[4096];  // own hs, k8-swizzled
  __shared__ float xts[64], xto[64];

  // ---- persistent per-kernel register loads (shared by both batch units)
  half8 Aw1[2][2];
#pragma unroll
  for (int q = 0; q < 2; ++q)
#pragma unroll
    for (int ks = 0; ks < 2; ++ks)
      Aw1[q][ks] = *(const half8*)&w1f[((((2 * wv + q) * 2 + ks) * 64) + l) * 8];
  half8 Aw2[2], Awl[2];
#pragma unroll
  for (int ks = 0; ks < 2; ++ks) {
    Aw2[ks] = *(const half8*)&w2f[(((wv * 2 + ks) * 64) + l) * 8];
    Awl[ks] = *(const half8*)&wlf[(((wv * 2 + ks) * 64) + l) * 8];
  }
  half4 fpl4[4];
#pragma unroll
  for (int nt = 0; nt < 4; ++nt)
    fpl4[nt] = *(const half4*)&fplC[(((tile * 4 + wv) * 256) + nt * 64 + l) * 4];
  float bjR[2][4], w1xR[2][4];
#pragma unroll
  for (int q = 0; q < 2; ++q)
#pragma unroll
    for (int qq = 0; qq < 4; ++qq) {
      int j = (2 * wv + q) * 16 + lq * 4 + qq;
      bjR[q][qq] = b1[j];
      w1xR[q][qq] = w1[j];          // w1 row 0
    }
  float b2R[4], w2xR[4];
#pragma unroll
  for (int qq = 0; qq < 4; ++qq) {
    int o = wv * 16 + lq * 4 + qq;
    b2R[qq] = b2[o];
    w2xR[qq] = w2[o];               // w2 row 0
  }
  const int bit = wv >> 1;          // gate col j>=64 iff wv>=2

  for (int uu = 0; uu < 2; ++uu) {
    const int b = bA + uu * 32;
    const float* xt = inputs + (size_t)(b * 12 + tstep) * 2048;
    const _Float16* hsb = hs_in + (size_t)b * 131072;

    __syncthreads();   // LDS safe to overwrite

    if (t < 64) {
      xto[t] = xt[a + t];
    } else if (t < 128) {
      int m = t - 64;
      int ns = (m < 32) ? (halfBase + m) : (1024 + halfBase + m - 32);
      xts[m] = xt[ns];
    }
    for (int i = t; i < 512; i += 256) {
      int m = i >> 3, k8 = i & 7;
      int ns = (m < 32) ? (halfBase + m) : (1024 + halfBase + m - 32);
      half8 v  = *(const half8*)&hsb[(size_t)ns * 64 + k8 * 8];
      half8 vo = *(const half8*)&hsb[(size_t)(a + m) * 64 + k8 * 8];
      int mt = m >> 4, ks = k8 >> 2, kc = k8 & 3;
      *(half8*)&Asrc[(((mt * 2 + ks) * 64) + ((m & 15) | (kc << 4))) * 8] = v;
      *(half8*)&hsOwn[m * 64 + ((k8 ^ ((m >> 1) & 7)) * 8)] = vo;
    }
    __syncthreads();

    float xtsR[4], xtoR[4];
#pragma unroll
    for (int nt = 0; nt < 4; ++nt) {
      xtsR[nt] = xts[nt * 16 + li];
      xtoR[nt] = xto[nt * 16 + li];
    }

    // ---- P1 (swapped): C'[j][m] = w1^T x hs_src
#pragma unroll
    for (int nt = 0; nt < 4; ++nt) {
      half8 Ba = *(half8*)&Asrc[(((nt * 2 + 0) * 64) + l) * 8];
      half8 Bb = *(half8*)&Asrc[(((nt * 2 + 1) * 64) + l) * 8];
      const int n = 2 * ((nt & 1) * 16 + li) + bit;
#pragma unroll
      for (int q = 0; q < 2; ++q) {
        f32x4 acc;
#pragma unroll
        for (int qq = 0; qq < 4; ++qq)
          acc[qq] = bjR[q][qq] + xtsR[nt] * w1xR[q][qq];
        acc = mfma16(Aw1[q][0], Ba, acc);
        acc = mfma16(Aw1[q][1], Bb, acc);
        const int jt = 2 * wv + q;
        const int k0 = (jt & 3) * 16 + lq * 4;
        half4 g4;
#pragma unroll
        for (int qq = 0; qq < 4; ++qq)
          g4[qq] = (_Float16)fast_sigmoid(acc[qq]);
        const int fa = afr4(n, k0);
        if (nt < 2) {       // r-gates: rh = r * hsOwn
          half4 hv = *(half4*)&hsOwn[hso4(n, k0)];
          half4 r4 = g4 * hv;
          *(half4*)&A2f[fa] = r4;
        } else {            // u-gates
          *(half4*)&uF[fa] = g4;
        }
      }
    }
    __syncthreads();

    // ---- P2 (swapped): C'[o][n] = w2^T x rh; fused new = u*hs + (1-u)*c
#pragma unroll
    for (int nt = 0; nt < 4; ++nt) {
      half8 Ba = *(half8*)&A2f[(((nt * 2 + 0) * 64) + l) * 8];
      half8 Bb = *(half8*)&A2f[(((nt * 2 + 1) * 64) + l) * 8];
      f32x4 acc;
#pragma unroll
      for (int qq = 0; qq < 4; ++qq)
        acc[qq] = b2R[qq] + xtoR[nt] * w2xR[qq];
      acc = mfma16(Aw2[0], Ba, acc);
      acc = mfma16(Aw2[1], Bb, acc);
      const int n = nt * 16 + li;
      const int o0 = wv * 16 + lq * 4;
      half4 c4;
#pragma unroll
      for (int qq = 0; qq < 4; ++qq)
        c4[qq] = (_Float16)fast_tanh(acc[qq]);
      const int fa = afr4(n, o0);
      half4 uv = *(half4*)&uF[fa];
      half4 hv = *(half4*)&hsOwn[hso4(n, o0)];
      half4 one = {(_Float16)1.f, (_Float16)1.f, (_Float16)1.f, (_Float16)1.f};
      half4 nw = uv * hv + (one - uv) * c4;
      *(half4*)&Asrc[fa] = nw;
    }
    __syncthreads();

    // ---- P3 (swapped): C'[o][n] = wl^T x new + fplC; vector global store
#pragma unroll
    for (int nt = 0; nt < 4; ++nt) {
      half8 Ba = *(half8*)&Asrc[(((nt * 2 + 0) * 64) + l) * 8];
      half8 Bb = *(half8*)&Asrc[(((nt * 2 + 1) * 64) + l) * 8];
      f32x4 acc;
#pragma unroll
      for (int qq = 0; qq < 4; ++qq)
        acc[qq] = (float)fpl4[nt][qq];
      acc = mfma16(Awl[0], Ba, acc);
      acc = mfma16(Awl[1], Bb, acc);
      const int n = nt * 16 + li;
      const int o0 = wv * 16 + lq * 4;
      const size_t base = (size_t)b * 131072 + (size_t)(a + n) * 64 + o0;
      if (outF32) {
        float4 o4 = make_float4(acc[0], acc[1], acc[2], acc[3]);
        *(float4*)&((float*)hs_out_v)[base] = o4;
      } else {
        half4 o4;
#pragma unroll
        for (int qq = 0; qq < 4; ++qq) o4[qq] = (_Float16)acc[qq];
        *(half4*)&((_Float16*)hs_out_v)[base] = o4;
      }
    }
  }
}

// ---------------------------------------------------------------------------
extern "C" void kernel_launch(void* const* d_in, const int* in_sizes, int n_in,
                              void* d_out, int out_size, void* d_ws, size_t ws_size,
                              hipStream_t stream) {
  const float* h      = (const float*)d_in[0];
  const float* adj    = (const float*)d_in[1];
  const float* inputs = (const float*)d_in[2];
  const float* ew1    = (const float*)d_in[3];
  const float* eb1    = (const float*)d_in[4];
  const float* ew2    = (const float*)d_in[5];
  const float* eb2    = (const float*)d_in[6];
  const float* eps1   = (const float*)d_in[7];
  const float* bnw    = (const float*)d_in[8];
  const float* bnb    = (const float*)d_in[9];
  const float* w1     = (const float*)d_in[10];
  const float* b1     = (const float*)d_in[11];
  const float* w2     = (const float*)d_in[12];
  const float* b2     = (const float*)d_in[13];
  const float* wg     = (const float*)d_in[14];
  const float* bg     = (const float*)d_in[15];
  const float* wl_w   = (const float*)d_in[16];
  const float* wl_b   = (const float*)d_in[17];

  char* ws = (char*)d_ws;

  // ws layout (bytes):
  //  [0, 16777216)           h0 (fp16 hs ping)
  //  [16777216, 33554432)    h1 (fp16 hs pong)
  //    aliased pre-GRU inside h1: x1 (131072 f32), x2 (131072 f32),
  //      x1f (131072 f16), psum (64 f32) + pqsum (64 f32)
  //  [33554432, +262144)     fplC (131072 halfs)
  //  then w1f (8192 halfs), w2f (4096), wlf (4096)
  _Float16* h0H = (_Float16*)ws;
  _Float16* h1H = (_Float16*)(ws + 16777216);
  float* x1    = (float*)h1H;
  float* x2    = x1 + 131072;
  _Float16* x1f = (_Float16*)(x2 + 131072);
  float* psum  = (float*)(x1f + 131072);   // psum[64] then pqsum[64]
  float* pqsum = psum + 64;
  _Float16* fplC = (_Float16*)(ws + 33554432);
  _Float16* w1f  = fplC + 131072;
  _Float16* w2f  = w1f + 8192;
  _Float16* wlf  = w2f + 4096;

  extract1p<<<576, 256, 0, stream>>>(h, ew1, eb1, w1, w2, wl_w,
                                     x1, x1f, w1f, w2f, wlf, psum);
  extract2s<<<256, 256, 0, stream>>>(adj, x1, x1f, eps1, x2, psum, pqsum);
  extract4s<<<512, 256, 0, stream>>>(x2, psum, pqsum, bnw, bnb, ew2, eb2,
                                     wg, bg, wl_w, wl_b, fplC);

  dim3 grid(32, 32);
  // Step 0: reduced kernel (hs = 0), writes h0.
  gru_step_first<<<grid, 256, 0, stream>>>(h0H, inputs, w1, b1, w2, b2,
                                           fplC, wlf);
  // Steps 1..11: main kernel (exact R11 structure).
  for (int t = 1; t < 12; ++t) {
    const _Float16* ibuf = (t & 1) ? h0H : h1H;
    void* obuf; int of32 = 0;
    if (t == 11) { obuf = d_out; of32 = 1; }
    else obuf = (t & 1) ? (void*)h1H : (void*)h0H;
    gru_step<<<grid, 256, 0, stream>>>(ibuf, obuf, of32, inputs, t,
                                       w1, b1, w2, b2, fplC, w1f, w2f, wlf);
  }
}